// Round 3
// baseline (178.091 us; speedup 1.0000x reference)
//
#include <hip/hip_runtime.h>

// Mutual information of an 8192x8192 fp32 contingency table — single fused kernel.
// MI = sum_{C>0} C*log2(C) - sum_i mx_i*log2(mx_i) - sum_j my_j*log2(my_j)
// (exact rewrite: zero entries contribute nothing to the masked sums, so the
//  masked row/col sums equal the full marginals).
//
// Each of the 32x32 blocks streams its 256x256 tile (coalesced float4,
// register column accumulators, one shfl+LDS-stage per row partial), writes
// its row/col partial slices to ws, then participates in a decoupled
// completion protocol:
//   - per-row-panel counter: the 32nd arriver folds that panel's 32 partials
//     per row, computes -x*log2(x), atomicAdds into a single accumulator
//   - per-col-panel counter: same for columns
//   - global counter: the 1024th arriver reads the accumulator and writes out
// All cross-block data passes release (__threadfence before counter atomic)
// -> acquire (__threadfence after observing counter) pairs; atomics are
// device-scope on gfx950. No spin-waits anywhere (no co-residency assumption,
// though the grid IS fully co-resident: 37 KB LDS -> 4 blocks/CU x 256 CUs).

#define NROWS 8192
#define MCOLS 8192

__inline__ __device__ float waveReduceSum(float v) {
    #pragma unroll
    for (int off = 32; off > 0; off >>= 1)
        v += __shfl_xor(v, off, 64);
    return v;
}

__global__ __launch_bounds__(256) void mi_fused(const float* __restrict__ C,
                                                float* __restrict__ P_rows,
                                                float* __restrict__ P_cols,
                                                float* __restrict__ acc,
                                                int*   __restrict__ cnts,
                                                float* __restrict__ out) {
    const int bx = blockIdx.x;            // column-panel 0..31
    const int by = blockIdx.y;            // row-panel 0..31
    const int tcol = bx * 256, trow = by * 256;
    const int tid  = threadIdx.x;
    const int lane = tid & 63;
    const int wave = tid >> 6;

    // lds_row[r][k]: bank = (r*33 + k) % 32 = (r + k) % 32 -> conflict-free
    __shared__ float lds_row[256][33];
    __shared__ float lds_col[4][256];
    __shared__ float lds_s1[4];
    __shared__ float lds_red_r[4];
    __shared__ float lds_red_c[4];
    __shared__ int   flags;

    float c0 = 0.f, c1 = 0.f, c2 = 0.f, c3 = 0.f;
    float s1_local = 0.f;

    const float* base = C + (size_t)trow * MCOLS + tcol + lane * 4;

    #pragma unroll 8
    for (int i = 0; i < 64; ++i) {
        const int r = i * 4 + wave;       // tile row handled by this wave
        const float4 v = *reinterpret_cast<const float4*>(base + (size_t)r * MCOLS);

        // masked C*log2(C)
        float t0 = (v.x > 0.f) ? v.x * __log2f(v.x) : 0.f;
        float t1 = (v.y > 0.f) ? v.y * __log2f(v.y) : 0.f;
        float t2 = (v.z > 0.f) ? v.z * __log2f(v.z) : 0.f;
        float t3 = (v.w > 0.f) ? v.w * __log2f(v.w) : 0.f;
        s1_local += (t0 + t1) + (t2 + t3);

        // register column accumulators (thread always sees same 4 cols)
        c0 += v.x; c1 += v.y; c2 += v.z; c3 += v.w;

        // row partial: fold upper half onto lower, stage 32 values in LDS
        float p = (v.x + v.y) + (v.z + v.w);
        p += __shfl_xor(p, 32, 64);
        if (lane < 32) lds_row[r][lane] = p;
    }

    // stage column partials
    lds_col[wave][lane * 4 + 0] = c0;
    lds_col[wave][lane * 4 + 1] = c1;
    lds_col[wave][lane * 4 + 2] = c2;
    lds_col[wave][lane * 4 + 3] = c3;

    // s1 partial per wave (one butterfly per kernel, not per iteration)
    const float s1w = waveReduceSum(s1_local);
    if (lane == 0) lds_s1[wave] = s1w;

    __syncthreads();

    // transposed row reduce: thread t owns tile-row t (2-way alias = free)
    float rs = 0.f;
    #pragma unroll
    for (int k = 0; k < 32; ++k) rs += lds_row[tid][k];
    P_rows[(size_t)bx * NROWS + trow + tid] = rs;

    // column reduce: thread t owns tile-col t
    const float cs = (lds_col[0][tid] + lds_col[1][tid]) +
                     (lds_col[2][tid] + lds_col[3][tid]);
    P_cols[(size_t)by * MCOLS + tcol + tid] = cs;

    __threadfence();                       // release P_rows/P_cols slices

    if (tid == 0) {
        atomicAdd(acc, (lds_s1[0] + lds_s1[1]) + (lds_s1[2] + lds_s1[3]));
        int f = 0;
        if (atomicAdd(&cnts[by], 1)      == 31) f |= 1;   // last of row-panel by
        if (atomicAdd(&cnts[32 + bx], 1) == 31) f |= 2;   // last of col-panel bx
        flags = f;
    }
    __syncthreads();
    const int f = flags;                   // block-uniform

    if (f & 1) {                           // row-panel entropy for panel by
        __threadfence();                   // acquire: see all 32 writers
        float x = 0.f;
        #pragma unroll
        for (int k = 0; k < 32; ++k) x += P_rows[(size_t)k * NROWS + trow + tid];
        float e = (x > 0.f) ? x * __log2f(x) : 0.f;
        e = waveReduceSum(e);
        if (lane == 0) lds_red_r[wave] = e;
        __syncthreads();
        if (tid == 0)
            atomicAdd(acc, -((lds_red_r[0] + lds_red_r[1]) +
                             (lds_red_r[2] + lds_red_r[3])));
    }

    if (f & 2) {                           // col-panel entropy for panel bx
        __threadfence();
        float x = 0.f;
        #pragma unroll
        for (int k = 0; k < 32; ++k) x += P_cols[(size_t)k * MCOLS + tcol + tid];
        float e = (x > 0.f) ? x * __log2f(x) : 0.f;
        e = waveReduceSum(e);
        if (lane == 0) lds_red_c[wave] = e;
        __syncthreads();
        if (tid == 0)
            atomicAdd(acc, -((lds_red_c[0] + lds_red_c[1]) +
                             (lds_red_c[2] + lds_red_c[3])));
    }

    if (tid == 0) {
        __threadfence();                   // order our acc adds before the count
        if (atomicAdd(&cnts[64], 1) == 32 * 32 - 1) {
            // all 1024 blocks (incl. all panel folds) have contributed
            __threadfence();
            out[0] = atomicAdd(acc, 0.0f); // coherent read of final value
        }
    }
}

extern "C" void kernel_launch(void* const* d_in, const int* in_sizes, int n_in,
                              void* d_out, int out_size, void* d_ws, size_t ws_size,
                              hipStream_t stream) {
    const float* C = (const float*)d_in[0];
    float* ws     = (float*)d_ws;
    float* P_rows = ws;                    // 32*8192 (never read before written)
    float* P_cols = ws + 262144;           // 32*8192
    float* acc    = ws + 524288;           // 1 float
    int*   cnts   = (int*)(ws + 524289);   // 65 ints (row[32], col[32], fin)

    // zero only acc + counters (268 B); P slices are write-before-read
    hipMemsetAsync((void*)acc, 0, 512, stream);

    dim3 grid(MCOLS / 256, NROWS / 256);
    mi_fused<<<grid, 256, 0, stream>>>(C, P_rows, P_cols, acc, cnts, (float*)d_out);
}

// Round 4
// 55.548 us; speedup vs baseline: 3.2061x; 3.2061x over previous
//
#include <hip/hip_runtime.h>

// Mutual information of an 8192x8192 fp32 contingency table.
// MI = sum_{C>0} C*log2(C) - sum_i mx_i*log2(mx_i) - sum_j my_j*log2(my_j)
// (exact rewrite: zero entries contribute nothing to the masked sums, so the
//  masked row/col sums equal the full marginals).
//
// 3-kernel structure (NO device fences — round 3 showed agent-scope fences
// cause L2 writeback/invalidate storms, 6x slowdown; cross-kernel visibility
// comes free from the implicit end-of-kernel cache flush).
//
// Pass 1 (mi_main): 32x64 grid, 256 threads, each block owns a 256col x 128row
//   tile -> 2048 blocks = 8 blocks/CU = 32 waves/CU (max occupancy).
//   - coalesced float4 row-segment loads (1 KB per wave-iteration)
//   - register column accumulators (thread sees the same 4 cols every iter)
//   - row partials folded 3x in-register (shfl_xor 32/16/8) -> only 8 values
//     per row staged in padded LDS -> 8.7 KB LDS total
//   - partials written non-atomically to unique ws slots
// Pass 2 (mi_ep1, 64 blocks): fold panel partials per marginal, entropy terms,
//   distributed s1 sum -> 64 block partials.
// Pass 3 (mi_ep2, 1 wave): final 64-way sum -> out.

#define NROWS 8192
#define MCOLS 8192
#define TROWS 128          // tile rows
#define RPANELS 32         // col-panels (grid.x) -> partials per row
#define CPANELS 64         // row-panels (grid.y) -> partials per col

__inline__ __device__ float waveReduceSum(float v) {
    #pragma unroll
    for (int off = 32; off > 0; off >>= 1)
        v += __shfl_xor(v, off, 64);
    return v;
}

__global__ __launch_bounds__(256, 8) void mi_main(const float* __restrict__ C,
                                                  float* __restrict__ P_rows,
                                                  float* __restrict__ P_cols,
                                                  float* __restrict__ s1_arr) {
    const int bx = blockIdx.x;            // column-panel 0..31
    const int by = blockIdx.y;            // row-panel 0..63
    const int tcol = bx * 256, trow = by * TROWS;
    const int tid  = threadIdx.x;
    const int lane = tid & 63;
    const int wave = tid >> 6;

    // lds_row[r][k], stride 9: read phase lane t, fixed k -> bank (9t+k)%32,
    // gcd(9,32)=1 -> 64 lanes spread over all 32 banks (2-way alias = free)
    __shared__ float lds_row[TROWS][9];
    __shared__ float lds_col[4][256];
    __shared__ float lds_s1[4];

    float c0 = 0.f, c1 = 0.f, c2 = 0.f, c3 = 0.f;
    float s1_local = 0.f;

    const float* base = C + (size_t)trow * MCOLS + tcol + lane * 4;

    #pragma unroll 4
    for (int i = 0; i < TROWS / 4; ++i) {
        const int r = i * 4 + wave;       // tile row handled by this wave
        const float4 v = *reinterpret_cast<const float4*>(base + (size_t)r * MCOLS);

        // masked C*log2(C)
        float t0 = (v.x > 0.f) ? v.x * __log2f(v.x) : 0.f;
        float t1 = (v.y > 0.f) ? v.y * __log2f(v.y) : 0.f;
        float t2 = (v.z > 0.f) ? v.z * __log2f(v.z) : 0.f;
        float t3 = (v.w > 0.f) ? v.w * __log2f(v.w) : 0.f;
        s1_local += (t0 + t1) + (t2 + t3);

        // register column accumulators
        c0 += v.x; c1 += v.y; c2 += v.z; c3 += v.w;

        // row partial: fold 64 -> 8 in-register, stage 8 values in LDS
        float p = (v.x + v.y) + (v.z + v.w);
        p += __shfl_xor(p, 32, 64);
        p += __shfl_xor(p, 16, 64);
        p += __shfl_xor(p,  8, 64);
        if (lane < 8) lds_row[r][lane] = p;
    }

    // stage column partials
    lds_col[wave][lane * 4 + 0] = c0;
    lds_col[wave][lane * 4 + 1] = c1;
    lds_col[wave][lane * 4 + 2] = c2;
    lds_col[wave][lane * 4 + 3] = c3;

    // s1 partial per wave
    const float s1w = waveReduceSum(s1_local);
    if (lane == 0) lds_s1[wave] = s1w;

    __syncthreads();

    // row reduce: thread t (t<128) owns tile-row t
    if (tid < TROWS) {
        float rs = 0.f;
        #pragma unroll
        for (int k = 0; k < 8; ++k) rs += lds_row[tid][k];
        P_rows[(size_t)bx * NROWS + trow + tid] = rs;
    }

    // column reduce: thread t owns tile-col t
    const float cs = (lds_col[0][tid] + lds_col[1][tid]) +
                     (lds_col[2][tid] + lds_col[3][tid]);
    P_cols[(size_t)by * MCOLS + tcol + tid] = cs;

    if (tid == 0)
        s1_arr[by * RPANELS + bx] = (lds_s1[0] + lds_s1[1]) + (lds_s1[2] + lds_s1[3]);
}

// 64 blocks: b<32 -> row marginals (fold 32 panels), b>=32 -> col marginals
// (fold 64 panels). Each block also folds 32 s1 entries.
__global__ __launch_bounds__(256) void mi_ep1(const float* __restrict__ P_rows,
                                              const float* __restrict__ P_cols,
                                              const float* __restrict__ s1_arr,
                                              float* __restrict__ partials) {
    const int b    = blockIdx.x;
    const int tid  = threadIdx.x;
    const int lane = tid & 63;
    const int wave = tid >> 6;
    const int idx  = ((b & 31) << 8) + tid;      // marginal index 0..8191

    float x = 0.f;
    if (b < 32) {
        #pragma unroll
        for (int k = 0; k < RPANELS; ++k) x += P_rows[(size_t)k * NROWS + idx];
    } else {
        #pragma unroll
        for (int k = 0; k < CPANELS; ++k) x += P_cols[(size_t)k * MCOLS + idx];
    }

    float acc = (x > 0.f) ? -x * __log2f(x) : 0.f;   // entropy enters negated
    if (tid < 32) acc += s1_arr[b * 32 + tid];       // distributed s1 sum (2048 total)

    acc = waveReduceSum(acc);
    __shared__ float lds[4];
    if (lane == 0) lds[wave] = acc;
    __syncthreads();
    if (tid == 0) partials[b] = (lds[0] + lds[1]) + (lds[2] + lds[3]);
}

__global__ void mi_ep2(const float* __restrict__ partials,
                       float* __restrict__ out) {
    float v = partials[threadIdx.x];  // exactly 64 threads
    v = waveReduceSum(v);
    if (threadIdx.x == 0) out[0] = v;
}

extern "C" void kernel_launch(void* const* d_in, const int* in_sizes, int n_in,
                              void* d_out, int out_size, void* d_ws, size_t ws_size,
                              hipStream_t stream) {
    const float* C = (const float*)d_in[0];
    float* ws      = (float*)d_ws;
    float* P_rows  = ws;                    // 32*8192   = 1 MB
    float* P_cols  = ws + 262144;           // 64*8192   = 2 MB
    float* s1_arr  = ws + 786432;           // 2048
    float* parts   = ws + 788480;           // 64
    // all slots write-before-read every call -> no memset needed

    dim3 grid(MCOLS / 256, NROWS / TROWS);  // 32 x 64 = 2048 blocks
    mi_main<<<grid, 256, 0, stream>>>(C, P_rows, P_cols, s1_arr);
    mi_ep1<<<64, 256, 0, stream>>>(P_rows, P_cols, s1_arr, parts);
    mi_ep2<<<1, 64, 0, stream>>>(parts, (float*)d_out);
}

// Round 5
// 55.148 us; speedup vs baseline: 3.2293x; 1.0073x over previous
//
#include <hip/hip_runtime.h>

// Mutual information of an 8192x8192 fp32 contingency table.
// MI = sum_{C>0} C*log2(C) - sum_i mx_i*log2(mx_i) - sum_j my_j*log2(my_j)
// (exact rewrite: zero entries contribute nothing to the masked sums, so the
//  masked row/col sums equal the full marginals).
//
// Round-5 variant: longer contiguous DRAM runs. Each block owns a
// 1024col x 64row tile (grid 8 x 128 = 1024 blocks); each wave-iteration
// issues 4 consecutive float4 loads = one contiguous 4 KB run (vs 1 KB
// bursts at 32 KB stride before) -> fewer, longer HBM streams + 4x MLP.
// Row partials folded 64->8 in-register (3 shfls per 4 KB, 1/4 the prior
// cross-lane rate); 16 register column accumulators per thread.
// NO device fences anywhere (round 3: fence storms -> 6x slowdown).

#define NROWS 8192
#define MCOLS 8192
#define SW    1024         // strip (tile) width in cols
#define TROWS 64           // tile rows
#define RPANELS 8          // col-strips  -> partials per row
#define CPANELS 128        // row-panels  -> partials per col

__inline__ __device__ float waveReduceSum(float v) {
    #pragma unroll
    for (int off = 32; off > 0; off >>= 1)
        v += __shfl_xor(v, off, 64);
    return v;
}

__global__ __launch_bounds__(256, 4) void mi_main(const float* __restrict__ C,
                                                  float* __restrict__ P_rows,
                                                  float* __restrict__ P_cols,
                                                  float* __restrict__ s1_arr) {
    const int bx = blockIdx.x;            // col-strip 0..7
    const int by = blockIdx.y;            // row-panel 0..127
    const int tcol = bx * SW, trow = by * TROWS;
    const int tid  = threadIdx.x;
    const int lane = tid & 63;
    const int wave = tid >> 6;

    // lds_row[r][k], stride 9: gcd(9,32)=1 -> reads spread all 32 banks
    __shared__ float lds_row[TROWS][9];
    __shared__ float lds_col[4][SW];
    __shared__ float lds_s1[4];

    float4 c0 = {0,0,0,0}, c1 = {0,0,0,0}, c2 = {0,0,0,0}, c3 = {0,0,0,0};
    float s1_local = 0.f;

    const float* base = C + (size_t)trow * MCOLS + tcol + lane * 4;

    #pragma unroll 4
    for (int i = 0; i < TROWS / 4; ++i) {
        const int r = i * 4 + wave;       // tile row handled by this wave
        const float4* rp = reinterpret_cast<const float4*>(base + (size_t)r * MCOLS);
        // one contiguous 4 KB run per wave: 4 back-to-back 1 KB chunks
        const float4 v0 = rp[0];          // cols lane*4 +   0 ..
        const float4 v1 = rp[64];         // cols lane*4 + 256 ..
        const float4 v2 = rp[128];        // cols lane*4 + 512 ..
        const float4 v3 = rp[192];        // cols lane*4 + 768 ..

        // masked C*log2(C), 16 elements
        float s = 0.f;
        s += (v0.x > 0.f) ? v0.x * __log2f(v0.x) : 0.f;
        s += (v0.y > 0.f) ? v0.y * __log2f(v0.y) : 0.f;
        s += (v0.z > 0.f) ? v0.z * __log2f(v0.z) : 0.f;
        s += (v0.w > 0.f) ? v0.w * __log2f(v0.w) : 0.f;
        s += (v1.x > 0.f) ? v1.x * __log2f(v1.x) : 0.f;
        s += (v1.y > 0.f) ? v1.y * __log2f(v1.y) : 0.f;
        s += (v1.z > 0.f) ? v1.z * __log2f(v1.z) : 0.f;
        s += (v1.w > 0.f) ? v1.w * __log2f(v1.w) : 0.f;
        s += (v2.x > 0.f) ? v2.x * __log2f(v2.x) : 0.f;
        s += (v2.y > 0.f) ? v2.y * __log2f(v2.y) : 0.f;
        s += (v2.z > 0.f) ? v2.z * __log2f(v2.z) : 0.f;
        s += (v2.w > 0.f) ? v2.w * __log2f(v2.w) : 0.f;
        s += (v3.x > 0.f) ? v3.x * __log2f(v3.x) : 0.f;
        s += (v3.y > 0.f) ? v3.y * __log2f(v3.y) : 0.f;
        s += (v3.z > 0.f) ? v3.z * __log2f(v3.z) : 0.f;
        s += (v3.w > 0.f) ? v3.w * __log2f(v3.w) : 0.f;
        s1_local += s;

        // register column accumulators (thread sees the same 16 cols each iter)
        c0.x += v0.x; c0.y += v0.y; c0.z += v0.z; c0.w += v0.w;
        c1.x += v1.x; c1.y += v1.y; c1.z += v1.z; c1.w += v1.w;
        c2.x += v2.x; c2.y += v2.y; c2.z += v2.z; c2.w += v2.w;
        c3.x += v3.x; c3.y += v3.y; c3.z += v3.z; c3.w += v3.w;

        // row partial over all 16 values; fold 64 -> 8 lanes, stage in LDS
        float p = ((v0.x + v0.y) + (v0.z + v0.w)) + ((v1.x + v1.y) + (v1.z + v1.w))
                + ((v2.x + v2.y) + (v2.z + v2.w)) + ((v3.x + v3.y) + (v3.z + v3.w));
        p += __shfl_xor(p, 32, 64);
        p += __shfl_xor(p, 16, 64);
        p += __shfl_xor(p,  8, 64);
        if (lane < 8) lds_row[r][lane] = p;
    }

    // stage column partials (float4 LDS stores, conflict-free)
    *reinterpret_cast<float4*>(&lds_col[wave][          lane * 4]) = c0;
    *reinterpret_cast<float4*>(&lds_col[wave][256     + lane * 4]) = c1;
    *reinterpret_cast<float4*>(&lds_col[wave][512     + lane * 4]) = c2;
    *reinterpret_cast<float4*>(&lds_col[wave][768     + lane * 4]) = c3;

    const float s1w = waveReduceSum(s1_local);
    if (lane == 0) lds_s1[wave] = s1w;

    __syncthreads();

    // row reduce: thread t (t<64) owns tile-row t
    if (tid < TROWS) {
        float rs = 0.f;
        #pragma unroll
        for (int k = 0; k < 8; ++k) rs += lds_row[tid][k];
        P_rows[(size_t)bx * NROWS + trow + tid] = rs;
    }

    // column reduce: thread t owns local cols t, t+256, t+512, t+768
    #pragma unroll
    for (int q = 0; q < 4; ++q) {
        const int j = q * 256 + tid;
        const float cs = (lds_col[0][j] + lds_col[1][j]) +
                         (lds_col[2][j] + lds_col[3][j]);
        P_cols[(size_t)by * MCOLS + tcol + j] = cs;
    }

    if (tid == 0)
        s1_arr[by * RPANELS + bx] = (lds_s1[0] + lds_s1[1]) + (lds_s1[2] + lds_s1[3]);
}

// 64 blocks: b<32 -> row marginals (fold 8 strips), b>=32 -> col marginals
// (fold 128 panels). Each block also folds 16 s1 entries.
__global__ __launch_bounds__(256) void mi_ep1(const float* __restrict__ P_rows,
                                              const float* __restrict__ P_cols,
                                              const float* __restrict__ s1_arr,
                                              float* __restrict__ partials) {
    const int b    = blockIdx.x;
    const int tid  = threadIdx.x;
    const int lane = tid & 63;
    const int wave = tid >> 6;
    const int idx  = ((b & 31) << 8) + tid;      // marginal index 0..8191

    float x = 0.f;
    if (b < 32) {
        #pragma unroll
        for (int k = 0; k < RPANELS; ++k) x += P_rows[(size_t)k * NROWS + idx];
    } else {
        #pragma unroll 16
        for (int k = 0; k < CPANELS; ++k) x += P_cols[(size_t)k * MCOLS + idx];
    }

    float acc = (x > 0.f) ? -x * __log2f(x) : 0.f;   // entropy enters negated
    if (tid < 16) acc += s1_arr[b * 16 + tid];       // distributed s1 sum (1024 total)

    acc = waveReduceSum(acc);
    __shared__ float lds[4];
    if (lane == 0) lds[wave] = acc;
    __syncthreads();
    if (tid == 0) partials[b] = (lds[0] + lds[1]) + (lds[2] + lds[3]);
}

__global__ void mi_ep2(const float* __restrict__ partials,
                       float* __restrict__ out) {
    float v = partials[threadIdx.x];  // exactly 64 threads
    v = waveReduceSum(v);
    if (threadIdx.x == 0) out[0] = v;
}

extern "C" void kernel_launch(void* const* d_in, const int* in_sizes, int n_in,
                              void* d_out, int out_size, void* d_ws, size_t ws_size,
                              hipStream_t stream) {
    const float* C = (const float*)d_in[0];
    float* ws      = (float*)d_ws;
    float* P_rows  = ws;                         // 8  * 8192
    float* P_cols  = ws + 65536;                 // 128* 8192 = 4 MB
    float* s1_arr  = ws + 65536 + 1048576;       // 1024
    float* parts   = ws + 65536 + 1048576 + 1024;// 64
    // all slots write-before-read every call -> no memset needed

    dim3 grid(MCOLS / SW, NROWS / TROWS);        // 8 x 128 = 1024 blocks
    mi_main<<<grid, 256, 0, stream>>>(C, P_rows, P_cols, s1_arr);
    mi_ep1<<<64, 256, 0, stream>>>(P_rows, P_cols, s1_arr, parts);
    mi_ep2<<<1, 64, 0, stream>>>(parts, (float*)d_out);
}